// Round 4
// baseline (4429.741 us; speedup 1.0000x reference)
//
#include <hip/hip_runtime.h>
#include <hip/hip_bf16.h>

// LSTM B=32,T=512,D=512,H=1024, persistent kernel.
// R8 = R5 structure + cached-broadcast h reads.
//  - Release: REVERTED to R5 (all 8 waves poll the 64 flags relaxed with
//    s_sleep backoff). R7's wave7+LDS mailbox cost ~0.45us/step.
//  - NEW: consumer h reads are NORMAL cached uint4 loads instead of
//    agent-scope (L2-bypassing) atomics. Freshness guaranteed by an
//    agent-scope ACQUIRE fence (buffer_inv) between flag detect and the
//    loads: producer's sc1 stores are at the coherent point before its
//    flag is visible, and the fence invalidates the stale L1/L2 lines
//    cached from this ping-pong buffer's use 2 steps ago.
//    Effect: the 8 MB/step all-to-all h burst through L3 becomes
//    first-toucher-per-XCD fetch + L2 hits (~1-2 MB/step), and per-load
//    latency drops from contended-L3 to L2-hit for most fragments.
//  - Producer path EXACTLY R5: stage->syncC->tid<256 sc1 8B atomic
//    stores->vmcnt(0)->syncD->tid0 relaxed flag store.
//  - zpart [32][16] (stride-16 epilogue reads are exactly 2-way = free).

#define B_   32
#define T_   512
#define D_   512
#define H_   1024
#define KTOT 1536
#define N4H  4096
#define NBLK 64

typedef __bf16 bf16_t;
typedef __bf16 bf16x8 __attribute__((ext_vector_type(8)));
typedef float f32x4 __attribute__((ext_vector_type(4)));

#define MFMA16(a, b, c) __builtin_amdgcn_mfma_f32_16x16x32_bf16(a, b, c, 0, 0, 0)

// ---------------------------------------------------------------------------
__global__ void wconv_kernel(const float* __restrict__ Wx,
                             const float* __restrict__ Wh,
                             bf16_t* __restrict__ Wt) {
    __shared__ float tile[32][33];
    int k0 = blockIdx.x * 32;
    int n0 = blockIdx.y * 32;
    int tx = threadIdx.x;
    int ty = threadIdx.y;
    for (int i = ty; i < 32; i += 8) {
        int k = k0 + i;
        float v = (k < H_) ? Wh[(size_t)k * N4H + n0 + tx]
                           : Wx[(size_t)(k - H_) * N4H + n0 + tx];
        tile[i][tx] = v;
    }
    __syncthreads();
    for (int i = ty; i < 32; i += 8)
        Wt[(size_t)(n0 + i) * KTOT + k0 + tx] = (bf16_t)tile[tx][i];
}

// ---------------------------------------------------------------------------
// X -> packed uint32 per element: low16 = bf16(hi), high16 = bf16(residual).
__global__ void xconv_kernel(const float4* __restrict__ X,
                             uint4* __restrict__ Xpk) {
    int i = blockIdx.x * blockDim.x + threadIdx.x;
    float4 v = X[i];
    float arr[4] = {v.x, v.y, v.z, v.w};
    unsigned pk[4];
#pragma unroll
    for (int j = 0; j < 4; ++j) {
        bf16_t h = (bf16_t)arr[j];
        bf16_t l = (bf16_t)(arr[j] - (float)h);
        pk[j] = (unsigned)__builtin_bit_cast(unsigned short, h) |
                ((unsigned)__builtin_bit_cast(unsigned short, l) << 16);
    }
    Xpk[i] = make_uint4(pk[0], pk[1], pk[2], pk[3]);
}

// ---------------------------------------------------------------------------
__device__ __forceinline__ void unpack16(const unsigned short* s,
                                         bf16x8* hi, bf16x8* lo) {
#pragma unroll
    for (int j = 0; j < 8; ++j) {
        (*hi)[j] = __builtin_bit_cast(bf16_t, s[2 * j]);
        (*lo)[j] = __builtin_bit_cast(bf16_t, s[2 * j + 1]);
    }
}

// ---------------------------------------------------------------------------
// Block b owns h-cols [16b,16b+16). Wave w: h-k in [128w,128w+128) (4 kb) +
// x-k in [1024+64w,1024+64w+64) (2 kb), all 4 gates. hpk ping-pong,
// frag-major layout; h WRITES via agent-scope atomics, h READS via normal
// cached loads guarded by an agent acquire fence.
__global__ __launch_bounds__(512, 2) void lstm_kernel(
    const bf16_t* __restrict__ Wt,
    const unsigned* __restrict__ Xpk,
    unsigned* __restrict__ hpk,
    const float* __restrict__ bias,
    const int* __restrict__ seqlen,
    float* __restrict__ out,
    unsigned* __restrict__ flags) {
    __shared__ float zpart[8][4][32][16];  // 64 KB partial sums (stride 16:
                                           // epilogue reads exactly 2-way)
    __shared__ unsigned stage[512];        // 2 KB h-store stage

    const int tid  = threadIdx.x;
    const int w    = tid >> 6;
    const int lane = tid & 63;
    const int quad = lane >> 4;
    const int lcol = lane & 15;
    const int hc0  = blockIdx.x * 16;
    const int HW_  = 32768;                // uints per h buffer (B_*H_)

    // Weight fragments: 4 gates x 6 k-iters (4 h + 2 x), loaded once.
    bf16x8 wreg[24];
#pragma unroll
    for (int g = 0; g < 4; ++g)
#pragma unroll
        for (int it = 0; it < 6; ++it) {
            int k = (it < 4) ? (w * 128 + it * 32)
                             : (1024 + w * 64 + (it - 4) * 32);
            wreg[g * 6 + it] = *(const bf16x8*)(
                Wt + (size_t)(g * H_ + hc0 + lcol) * KTOT + k + quad * 8);
        }

    // Epilogue mapping: 512 threads = one (batch,col) element each.
    const int eb = tid >> 4, ec = tid & 15;
    const int col = hc0 + ec;
    float creg = 0.f;
    const float b0 = bias[col];
    const float b1 = bias[H_ + col];
    const float b2 = bias[2 * H_ + col];
    const float b3 = bias[3 * H_ + col];
    const int slm1 = seqlen[eb] - 1;
    // LDS stage index (destination-ordered within this block's h region).
    const int stageIdx = (eb >> 4) * 256 + ((ec >> 3) * 16 + (eb & 15)) * 8 +
                         (ec & 7);
    // Store-phase constants (tid<256: one contiguous 8B store per thread).
    const int kbB  = (hc0 >> 5) * 1024;    // k-block base (uints)
    const int qlo  = (hc0 >> 4) & 1;       // which quad-pair within k-block
    const int dst0 = kbB + (tid >> 7) * 512 + qlo * 256 + (tid & 127) * 2;

#pragma unroll 1
    for (int t = 0; t < T_; ++t) {
        const unsigned* hr = hpk + (size_t)(t & 1) * HW_;
        unsigned*       hw = hpk + (size_t)((t + 1) & 1) * HW_;

        f32x4 acc[8];
#pragma unroll
        for (int i = 0; i < 8; ++i) acc[i] = (f32x4){0.f, 0.f, 0.f, 0.f};

        // ---- x part: independent of h(t-1), fills the wait window ----
#pragma unroll
        for (int itx = 0; itx < 2; ++itx) {
            int kx = w * 64 + itx * 32 + quad * 8;
            union { uint4 q[2]; unsigned short s[16]; } u0, u1;
            const unsigned* p0 = Xpk + ((size_t)lcol * T_ + t) * D_ + kx;
            const unsigned* p1 = Xpk + ((size_t)(lcol + 16) * T_ + t) * D_ + kx;
            u0.q[0] = *(const uint4*)p0;
            u0.q[1] = *(const uint4*)(p0 + 4);
            u1.q[0] = *(const uint4*)p1;
            u1.q[1] = *(const uint4*)(p1 + 4);
            bf16x8 a0h, a0l, a1h, a1l;
            unpack16(u0.s, &a0h, &a0l);
            unpack16(u1.s, &a1h, &a1l);
#pragma unroll
            for (int g = 0; g < 4; ++g) {
                bf16x8 wv = wreg[g * 6 + 4 + itx];
                acc[g * 2]     = MFMA16(a0h, wv, acc[g * 2]);
                acc[g * 2]     = MFMA16(a0l, wv, acc[g * 2]);
                acc[g * 2 + 1] = MFMA16(a1h, wv, acc[g * 2 + 1]);
                acc[g * 2 + 1] = MFMA16(a1l, wv, acc[g * 2 + 1]);
            }
        }

        // ---- wait for h(t-1): all waves poll relaxed, then ACQUIRE ----
        {
            const unsigned tgt = (unsigned)t;
            for (;;) {
                unsigned v = __hip_atomic_load(flags + lane, __ATOMIC_RELAXED,
                                               __HIP_MEMORY_SCOPE_AGENT);
                if (__all((int)(v >= tgt))) break;
                __builtin_amdgcn_s_sleep(1);
            }
            // Invalidate stale L1/L2 lines (this buffer's data from t-2);
            // producer data is at the coherent point before its flag.
            __builtin_amdgcn_fence(__ATOMIC_ACQUIRE, "agent");
        }

        // ---- h part: normal cached loads (L2-shared across co-XCD blocks),
        //      all 8 fragments issued back-to-back, then unpack + MFMA ----
        union Raw { uint4 q[2]; unsigned short s[16]; };
        Raw r[8];
#pragma unroll
        for (int it = 0; it < 4; ++it) {
            const uint4* q = (const uint4*)(hr + (w * 4 + it) * 1024 + lane * 8);
            r[it * 2].q[0]     = q[0];      // batches 0..15, 32B contiguous
            r[it * 2].q[1]     = q[1];
            r[it * 2 + 1].q[0] = q[128];    // batches 16..31 (+512 uints)
            r[it * 2 + 1].q[1] = q[129];
        }
#pragma unroll
        for (int it = 0; it < 4; ++it) {
            bf16x8 a0h, a0l, a1h, a1l;
            unpack16(r[it * 2].s, &a0h, &a0l);
            unpack16(r[it * 2 + 1].s, &a1h, &a1l);
#pragma unroll
            for (int g = 0; g < 4; ++g) {
                bf16x8 wv = wreg[g * 6 + it];
                acc[g * 2]     = MFMA16(a0h, wv, acc[g * 2]);
                acc[g * 2]     = MFMA16(a0l, wv, acc[g * 2]);
                acc[g * 2 + 1] = MFMA16(a1h, wv, acc[g * 2 + 1]);
                acc[g * 2 + 1] = MFMA16(a1l, wv, acc[g * 2 + 1]);
            }
        }

#pragma unroll
        for (int g = 0; g < 4; ++g)
#pragma unroll
            for (int r4 = 0; r4 < 4; ++r4) {
                zpart[w][g][quad * 4 + r4][lcol]      = acc[g * 2][r4];
                zpart[w][g][16 + quad * 4 + r4][lcol] = acc[g * 2 + 1][r4];
            }
        __syncthreads();  // A: zpart complete

        // Epilogue (all 512 threads).
        float zi = b0, zf = b1, zg = b2, zo = b3;
#pragma unroll
        for (int ss = 0; ss < 8; ++ss) {
            zi += zpart[ss][0][eb][ec];
            zf += zpart[ss][1][eb][ec];
            zg += zpart[ss][2][eb][ec];
            zo += zpart[ss][3][eb][ec];
        }
        float ig = 1.f / (1.f + __expf(-zi));
        float fg = 1.f / (1.f + __expf(-zf));
        float og = 1.f / (1.f + __expf(-zo));
        float gg = 1.f - 2.f / (__expf(2.f * zg) + 1.f);
        creg = fg * creg + ig * gg;
        float hn = og * (1.f - 2.f / (__expf(2.f * creg) + 1.f));
        bf16_t hh = (bf16_t)hn;
        bf16_t hl = (bf16_t)(hn - (float)hh);
        unsigned pk = (unsigned)__builtin_bit_cast(unsigned short, hh) |
                      ((unsigned)__builtin_bit_cast(unsigned short, hl) << 16);
        stage[stageIdx] = pk;
        if (slm1 == t) out[eb * H_ + col] = hn;

        __syncthreads();  // C: stage complete (zpart reads also done)

        if (tid < 256) {
            unsigned long long val = ((const unsigned long long*)stage)[tid];
            __hip_atomic_store((unsigned long long*)(hw + dst0), val,
                               __ATOMIC_RELAXED, __HIP_MEMORY_SCOPE_AGENT);
        }
        // Drain stores (they are at the coherent point when vmcnt hits 0),
        // syncD, then one plain agent flag store.
        asm volatile("s_waitcnt vmcnt(0)" ::: "memory");
        __syncthreads();  // D: all stores drained, stage reads done
        if (tid == 0)
            __hip_atomic_store(flags + blockIdx.x, (unsigned)(t + 1),
                               __ATOMIC_RELAXED, __HIP_MEMORY_SCOPE_AGENT);
    }
}

// ---------------------------------------------------------------------------
extern "C" void kernel_launch(void* const* d_in, const int* in_sizes, int n_in,
                              void* d_out, int out_size, void* d_ws, size_t ws_size,
                              hipStream_t stream) {
    const float* inputs = (const float*)d_in[0];
    const int*   seqlen = (const int*)d_in[1];
    const float* Wx     = (const float*)d_in[2];
    const float* Wh     = (const float*)d_in[3];
    const float* bias   = (const float*)d_in[4];
    float* out = (float*)d_out;

    char* ws = (char*)d_ws;
    size_t o = 0;
    bf16_t*   Wt    = (bf16_t*)(ws + o);   o += (size_t)N4H * KTOT * 2;   // 12.6MB
    unsigned* Xpk   = (unsigned*)(ws + o); o += (size_t)B_ * T_ * D_ * 4; // 33.6MB
    unsigned* hpk   = (unsigned*)(ws + o); o += (size_t)2 * B_ * H_ * 4;  // 256KB
    unsigned* flags = (unsigned*)(ws + o); o += 4096;

    wconv_kernel<<<dim3(48, 128), dim3(32, 8), 0, stream>>>(Wx, Wh, Wt);
    xconv_kernel<<<(B_ * T_ * D_ / 4) / 256, 256, 0, stream>>>(
        (const float4*)inputs, (uint4*)Xpk);
    hipMemsetAsync(hpk, 0, (size_t)B_ * H_ * 4, stream);  // ping p=0 zeros
    hipMemsetAsync(flags, 0, 4096, stream);               // readiness flags

    lstm_kernel<<<NBLK, 512, 0, stream>>>(Wt, Xpk, hpk, bias, seqlen, out, flags);
}

// Round 5
// 3533.795 us; speedup vs baseline: 1.2535x; 1.2535x over previous
//
#include <hip/hip_runtime.h>
#include <hip/hip_bf16.h>

// LSTM B=32,T=512,D=512,H=1024, persistent kernel.
// R9 = R5 structure with the flag protocol DELETED: self-synchronizing h.
//  - Each 8B h-granule (one atomic store) carries a 1-bit step tag in the
//    mantissa LSB of its even element's HI bf16 word. The LO residual is
//    recomputed from the TAGGED hi, so the tag is exactly absorbed by the
//    hi+lo pair -> zero added representation error (absmax unchanged).
//  - Consumers poll the data itself: load the 32 granules of their k-slice,
//    check all tags == (t>>1)&1, retry with s_sleep backoff. Tag-fresh
//    implies data-fresh (single 8B atomic store per granule).
//  - Producer tail after syncC = just the tid<256 coalesced 8B stores.
//    NO vmcnt drain, NO syncD, NO flag store. Same-thread same-address
//    coherence makes drains unnecessary across buffer reuse.
//  - Ping-pong safety (1-bit tag, 2 buffers): stale occupant of buffer
//    t&1 is step t-2 data tagged (t>>1)&1 ^ 1; a step-t+2 writer cannot
//    exist while any consumer polls for t (it would need that consumer's
//    t+1 tile first). Init: buf0 = 0x00 (tag 0, h=0 for t=0), buf1 = 0xFF
//    (tag 1 != expected 0 at t=1).
//  - Elastic pipeline: wave w's poll covers only its 8 producers' tiles;
//    the chip-wide max-of-64 lockstep becomes wave-granular slack.
//  - Barriers per step: 2 (syncA, syncC). launch_bounds (512,1): poll
//    liveness raises VGPRs; 64 blocks = 1 block/CU anyway.

#define B_   32
#define T_   512
#define D_   512
#define H_   1024
#define KTOT 1536
#define N4H  4096
#define NBLK 64

typedef __bf16 bf16_t;
typedef __bf16 bf16x8 __attribute__((ext_vector_type(8)));
typedef float f32x4 __attribute__((ext_vector_type(4)));

#define MFMA16(a, b, c) __builtin_amdgcn_mfma_f32_16x16x32_bf16(a, b, c, 0, 0, 0)

// ---------------------------------------------------------------------------
__global__ void wconv_kernel(const float* __restrict__ Wx,
                             const float* __restrict__ Wh,
                             bf16_t* __restrict__ Wt) {
    __shared__ float tile[32][33];
    int k0 = blockIdx.x * 32;
    int n0 = blockIdx.y * 32;
    int tx = threadIdx.x;
    int ty = threadIdx.y;
    for (int i = ty; i < 32; i += 8) {
        int k = k0 + i;
        float v = (k < H_) ? Wh[(size_t)k * N4H + n0 + tx]
                           : Wx[(size_t)(k - H_) * N4H + n0 + tx];
        tile[i][tx] = v;
    }
    __syncthreads();
    for (int i = ty; i < 32; i += 8)
        Wt[(size_t)(n0 + i) * KTOT + k0 + tx] = (bf16_t)tile[tx][i];
}

// ---------------------------------------------------------------------------
// X -> packed uint32 per element: low16 = bf16(hi), high16 = bf16(residual).
__global__ void xconv_kernel(const float4* __restrict__ X,
                             uint4* __restrict__ Xpk) {
    int i = blockIdx.x * blockDim.x + threadIdx.x;
    float4 v = X[i];
    float arr[4] = {v.x, v.y, v.z, v.w};
    unsigned pk[4];
#pragma unroll
    for (int j = 0; j < 4; ++j) {
        bf16_t h = (bf16_t)arr[j];
        bf16_t l = (bf16_t)(arr[j] - (float)h);
        pk[j] = (unsigned)__builtin_bit_cast(unsigned short, h) |
                ((unsigned)__builtin_bit_cast(unsigned short, l) << 16);
    }
    Xpk[i] = make_uint4(pk[0], pk[1], pk[2], pk[3]);
}

// ---------------------------------------------------------------------------
__device__ __forceinline__ void unpack16(const unsigned short* s,
                                         bf16x8* hi, bf16x8* lo) {
#pragma unroll
    for (int j = 0; j < 8; ++j) {
        (*hi)[j] = __builtin_bit_cast(bf16_t, s[2 * j]);
        (*lo)[j] = __builtin_bit_cast(bf16_t, s[2 * j + 1]);
    }
}

// ---------------------------------------------------------------------------
// Block b owns h-cols [16b,16b+16). Wave w: h-k in [128w,128w+128) (4 kb) +
// x-k in [1024+64w,1024+64w+64) (2 kb), all 4 gates. hpk ping-pong,
// frag-major layout, accessed only via agent-scope atomics (tag-polled).
__global__ __launch_bounds__(512, 1) void lstm_kernel(
    const bf16_t* __restrict__ Wt,
    const unsigned* __restrict__ Xpk,
    unsigned* __restrict__ hpk,
    const float* __restrict__ bias,
    const int* __restrict__ seqlen,
    float* __restrict__ out) {
    __shared__ float zpart[8][4][32][16];  // 64 KB partial sums (stride 16:
                                           // epilogue reads exactly 2-way)
    __shared__ unsigned stage[512];        // 2 KB h-store stage

    const int tid  = threadIdx.x;
    const int w    = tid >> 6;
    const int lane = tid & 63;
    const int quad = lane >> 4;
    const int lcol = lane & 15;
    const int hc0  = blockIdx.x * 16;
    const int HW_  = 32768;                // uints per h buffer (B_*H_)

    // Weight fragments: 4 gates x 6 k-iters (4 h + 2 x), loaded once.
    bf16x8 wreg[24];
#pragma unroll
    for (int g = 0; g < 4; ++g)
#pragma unroll
        for (int it = 0; it < 6; ++it) {
            int k = (it < 4) ? (w * 128 + it * 32)
                             : (1024 + w * 64 + (it - 4) * 32);
            wreg[g * 6 + it] = *(const bf16x8*)(
                Wt + (size_t)(g * H_ + hc0 + lcol) * KTOT + k + quad * 8);
        }

    // Epilogue mapping: 512 threads = one (batch,col) element each.
    const int eb = tid >> 4, ec = tid & 15;
    const int col = hc0 + ec;
    float creg = 0.f;
    const float b0 = bias[col];
    const float b1 = bias[H_ + col];
    const float b2 = bias[2 * H_ + col];
    const float b3 = bias[3 * H_ + col];
    const int slm1 = seqlen[eb] - 1;
    // LDS stage index (destination-ordered within this block's h region).
    const int stageIdx = (eb >> 4) * 256 + ((ec >> 3) * 16 + (eb & 15)) * 8 +
                         (ec & 7);
    // Store-phase constants (tid<256: one contiguous 8B store per thread).
    const int kbB  = (hc0 >> 5) * 1024;    // k-block base (uints)
    const int qlo  = (hc0 >> 4) & 1;       // which quad-pair within k-block
    const int dst0 = kbB + (tid >> 7) * 512 + qlo * 256 + (tid & 127) * 2;
    // Tag carrier: even-ec threads own the low (even) word of each granule.
    const unsigned short tagKeep = (ec & 1) ? (unsigned short)0xFFFFu
                                            : (unsigned short)0xFFFEu;

#pragma unroll 1
    for (int t = 0; t < T_; ++t) {
        const unsigned* hr = hpk + (size_t)(t & 1) * HW_;
        unsigned*       hw = hpk + (size_t)((t + 1) & 1) * HW_;

        f32x4 acc[8];
#pragma unroll
        for (int i = 0; i < 8; ++i) acc[i] = (f32x4){0.f, 0.f, 0.f, 0.f};

        // ---- x part: independent of h(t-1), fills the wait window ----
#pragma unroll
        for (int itx = 0; itx < 2; ++itx) {
            int kx = w * 64 + itx * 32 + quad * 8;
            union { uint4 q[2]; unsigned short s[16]; } u0, u1;
            const unsigned* p0 = Xpk + ((size_t)lcol * T_ + t) * D_ + kx;
            const unsigned* p1 = Xpk + ((size_t)(lcol + 16) * T_ + t) * D_ + kx;
            u0.q[0] = *(const uint4*)p0;
            u0.q[1] = *(const uint4*)(p0 + 4);
            u1.q[0] = *(const uint4*)p1;
            u1.q[1] = *(const uint4*)(p1 + 4);
            bf16x8 a0h, a0l, a1h, a1l;
            unpack16(u0.s, &a0h, &a0l);
            unpack16(u1.s, &a1h, &a1l);
#pragma unroll
            for (int g = 0; g < 4; ++g) {
                bf16x8 wv = wreg[g * 6 + 4 + itx];
                acc[g * 2]     = MFMA16(a0h, wv, acc[g * 2]);
                acc[g * 2]     = MFMA16(a0l, wv, acc[g * 2]);
                acc[g * 2 + 1] = MFMA16(a1h, wv, acc[g * 2 + 1]);
                acc[g * 2 + 1] = MFMA16(a1l, wv, acc[g * 2 + 1]);
            }
        }

        // ---- h part: tag-polled loads. Wave w depends only on its own 8
        //      producers; data is fresh iff every granule's tag bit == exp.
        union Raw { unsigned long long u[4]; unsigned short s[16]; };
        Raw r[8];
        const unsigned expBit = ((unsigned)t >> 1) & 1u;
        for (;;) {
#pragma unroll
            for (int it = 0; it < 4; ++it) {
                const unsigned long long* q = (const unsigned long long*)(
                    hr + (w * 4 + it) * 1024 + lane * 8);
#pragma unroll
                for (int j = 0; j < 4; ++j)
                    r[it * 2].u[j] = __hip_atomic_load(
                        q + j, __ATOMIC_RELAXED, __HIP_MEMORY_SCOPE_AGENT);
#pragma unroll
                for (int j = 0; j < 4; ++j)
                    r[it * 2 + 1].u[j] = __hip_atomic_load(
                        q + 256 + j, __ATOMIC_RELAXED, __HIP_MEMORY_SCOPE_AGENT);
            }
            unsigned bad = 0;
#pragma unroll
            for (int f = 0; f < 8; ++f)
#pragma unroll
                for (int j = 0; j < 4; ++j)
                    bad |= ((unsigned)r[f].u[j] ^ expBit) & 1u;
            if (__all(bad == 0)) break;
            __builtin_amdgcn_s_sleep(1);
        }
#pragma unroll
        for (int it = 0; it < 4; ++it) {
            bf16x8 a0h, a0l, a1h, a1l;
            unpack16(r[it * 2].s, &a0h, &a0l);
            unpack16(r[it * 2 + 1].s, &a1h, &a1l);
#pragma unroll
            for (int g = 0; g < 4; ++g) {
                bf16x8 wv = wreg[g * 6 + it];
                acc[g * 2]     = MFMA16(a0h, wv, acc[g * 2]);
                acc[g * 2]     = MFMA16(a0l, wv, acc[g * 2]);
                acc[g * 2 + 1] = MFMA16(a1h, wv, acc[g * 2 + 1]);
                acc[g * 2 + 1] = MFMA16(a1l, wv, acc[g * 2 + 1]);
            }
        }

#pragma unroll
        for (int g = 0; g < 4; ++g)
#pragma unroll
            for (int r4 = 0; r4 < 4; ++r4) {
                zpart[w][g][quad * 4 + r4][lcol]      = acc[g * 2][r4];
                zpart[w][g][16 + quad * 4 + r4][lcol] = acc[g * 2 + 1][r4];
            }
        __syncthreads();  // A: zpart complete

        // Epilogue (all 512 threads).
        float zi = b0, zf = b1, zg = b2, zo = b3;
#pragma unroll
        for (int ss = 0; ss < 8; ++ss) {
            zi += zpart[ss][0][eb][ec];
            zf += zpart[ss][1][eb][ec];
            zg += zpart[ss][2][eb][ec];
            zo += zpart[ss][3][eb][ec];
        }
        float ig = 1.f / (1.f + __expf(-zi));
        float fg = 1.f / (1.f + __expf(-zf));
        float og = 1.f / (1.f + __expf(-zo));
        float gg = 1.f - 2.f / (__expf(2.f * zg) + 1.f);
        creg = fg * creg + ig * gg;
        float hn = og * (1.f - 2.f / (__expf(2.f * creg) + 1.f));
        // Tag-embedded hi/lo split: force hi's mantissa LSB (even-ec threads
        // only) to the step tag, then recompute lo from the TAGGED hi so the
        // pair still sums to hn with full precision.
        const unsigned tagb = (((unsigned)t + 1u) >> 1) & 1u;
        bf16_t hh = (bf16_t)hn;
        unsigned short uh = __builtin_bit_cast(unsigned short, hh);
        uh = (unsigned short)((uh & tagKeep) | ((ec & 1) ? 0u : tagb));
        bf16_t hh2 = __builtin_bit_cast(bf16_t, uh);
        bf16_t hl = (bf16_t)(hn - (float)hh2);
        unsigned pk = (unsigned)uh |
                      ((unsigned)__builtin_bit_cast(unsigned short, hl) << 16);
        stage[stageIdx] = pk;
        if (slm1 == t) out[eb * H_ + col] = hn;

        __syncthreads();  // C: stage complete (zpart reads also done)

        // Producer tail: fire-and-forget coalesced 8B atomic stores. Tag
        // travels inside each granule -> no drain, no syncD, no flag.
        if (tid < 256) {
            unsigned long long val = ((const unsigned long long*)stage)[tid];
            __hip_atomic_store((unsigned long long*)(hw + dst0), val,
                               __ATOMIC_RELAXED, __HIP_MEMORY_SCOPE_AGENT);
        }
    }
}

// ---------------------------------------------------------------------------
extern "C" void kernel_launch(void* const* d_in, const int* in_sizes, int n_in,
                              void* d_out, int out_size, void* d_ws, size_t ws_size,
                              hipStream_t stream) {
    const float* inputs = (const float*)d_in[0];
    const int*   seqlen = (const int*)d_in[1];
    const float* Wx     = (const float*)d_in[2];
    const float* Wh     = (const float*)d_in[3];
    const float* bias   = (const float*)d_in[4];
    float* out = (float*)d_out;

    char* ws = (char*)d_ws;
    size_t o = 0;
    bf16_t*   Wt  = (bf16_t*)(ws + o);   o += (size_t)N4H * KTOT * 2;   // 12.6MB
    unsigned* Xpk = (unsigned*)(ws + o); o += (size_t)B_ * T_ * D_ * 4; // 33.6MB
    unsigned* hpk = (unsigned*)(ws + o); o += (size_t)2 * B_ * H_ * 4;  // 256KB

    wconv_kernel<<<dim3(48, 128), dim3(32, 8), 0, stream>>>(Wx, Wh, Wt);
    xconv_kernel<<<(B_ * T_ * D_ / 4) / 256, 256, 0, stream>>>(
        (const float4*)inputs, (uint4*)Xpk);
    // buf0: h=0 with tag bit 0 (= expected at t=0). buf1: 0xFF -> tag bit 1
    // (!= expected 0 at t=1) so uninitialized data can never false-match.
    hipMemsetAsync(hpk, 0x00, (size_t)B_ * H_ * 4, stream);
    hipMemsetAsync(hpk + (size_t)B_ * H_, 0xFF, (size_t)B_ * H_ * 4, stream);

    lstm_kernel<<<NBLK, 512, 0, stream>>>(Wt, Xpk, hpk, bias, seqlen, out);
}

// Round 8
// 3399.158 us; speedup vs baseline: 1.3032x; 1.0396x over previous
//
#include <hip/hip_runtime.h>
#include <hip/hip_bf16.h>

// LSTM B=32,T=512,D=512,H=1024, persistent kernel.
// R11 = R10 structure, but the wave0-consolidated h store uses ONLY the
// proven primitive (__hip_atomic_store 8B, agent scope) instead of R10b's
// hand-rolled global_store_dwordx4 sc1 asm (NaN'd: visibility semantics
// of the raw sc1 store are evidently NOT equivalent to the intrinsic).
//  - Subset release: wave w polls ONLY its 8 producers (blocks 8w..8w+7),
//    flags padded one 64B line per group, tight spin. Elastic pipeline.
//    Safety: union of all 8 waves' subsets (enforced by syncA) covers all
//    64 flags before any buffer overwrite -- invariant identical to R5.
//  - Wave0 store: 4 rounds x (64 lanes x consecutive 8B atomic stores) =
//    4 contiguous 512B bursts; byte-identical dst layout to R5's tid<256
//    store (verified: dst_ull = kbB/2 + qlo*128 + (j>>1)*256 + (j&1)*64
//    + lane == R5 mapping with s_ull = j*64+lane). Wave 0 drains its OWN
//    vmcnt, posts flag. syncD deleted; waves 1-7 run ahead into t+1.
//  - Everything else EXACTLY R5: zpart [32][16], x-before-poll, 8B
//    agent-atomic h loads, stage layout.

#define B_   32
#define T_   512
#define D_   512
#define H_   1024
#define KTOT 1536
#define N4H  4096
#define NBLK 64

typedef __bf16 bf16_t;
typedef __bf16 bf16x8 __attribute__((ext_vector_type(8)));
typedef float f32x4 __attribute__((ext_vector_type(4)));

#define MFMA16(a, b, c) __builtin_amdgcn_mfma_f32_16x16x32_bf16(a, b, c, 0, 0, 0)

// ---------------------------------------------------------------------------
__global__ void wconv_kernel(const float* __restrict__ Wx,
                             const float* __restrict__ Wh,
                             bf16_t* __restrict__ Wt) {
    __shared__ float tile[32][33];
    int k0 = blockIdx.x * 32;
    int n0 = blockIdx.y * 32;
    int tx = threadIdx.x;
    int ty = threadIdx.y;
    for (int i = ty; i < 32; i += 8) {
        int k = k0 + i;
        float v = (k < H_) ? Wh[(size_t)k * N4H + n0 + tx]
                           : Wx[(size_t)(k - H_) * N4H + n0 + tx];
        tile[i][tx] = v;
    }
    __syncthreads();
    for (int i = ty; i < 32; i += 8)
        Wt[(size_t)(n0 + i) * KTOT + k0 + tx] = (bf16_t)tile[tx][i];
}

// ---------------------------------------------------------------------------
// X -> packed uint32 per element: low16 = bf16(hi), high16 = bf16(residual).
__global__ void xconv_kernel(const float4* __restrict__ X,
                             uint4* __restrict__ Xpk) {
    int i = blockIdx.x * blockDim.x + threadIdx.x;
    float4 v = X[i];
    float arr[4] = {v.x, v.y, v.z, v.w};
    unsigned pk[4];
#pragma unroll
    for (int j = 0; j < 4; ++j) {
        bf16_t h = (bf16_t)arr[j];
        bf16_t l = (bf16_t)(arr[j] - (float)h);
        pk[j] = (unsigned)__builtin_bit_cast(unsigned short, h) |
                ((unsigned)__builtin_bit_cast(unsigned short, l) << 16);
    }
    Xpk[i] = make_uint4(pk[0], pk[1], pk[2], pk[3]);
}

// ---------------------------------------------------------------------------
__device__ __forceinline__ void unpack16(const unsigned short* s,
                                         bf16x8* hi, bf16x8* lo) {
#pragma unroll
    for (int j = 0; j < 8; ++j) {
        (*hi)[j] = __builtin_bit_cast(bf16_t, s[2 * j]);
        (*lo)[j] = __builtin_bit_cast(bf16_t, s[2 * j + 1]);
    }
}

// ---------------------------------------------------------------------------
// Block b owns h-cols [16b,16b+16). Wave w: h-k in [128w,128w+128) (4 kb,
// producers = blocks 8w..8w+7) + x-k in [1024+64w,1024+64w+64) (2 kb).
// hpk ping-pong, frag-major layout, accessed only via agent-scope ops.
__global__ __launch_bounds__(512, 2) void lstm_kernel(
    const bf16_t* __restrict__ Wt,
    const unsigned* __restrict__ Xpk,
    unsigned* __restrict__ hpk,
    const float* __restrict__ bias,
    const int* __restrict__ seqlen,
    float* __restrict__ out,
    unsigned* __restrict__ flags) {
    __shared__ float zpart[8][4][32][16];  // 64 KB partial sums (stride 16:
                                           // epilogue reads exactly 2-way)
    __shared__ unsigned stage[512];        // 2 KB h-store stage

    const int tid  = threadIdx.x;
    const int w    = tid >> 6;
    const int lane = tid & 63;
    const int quad = lane >> 4;
    const int lcol = lane & 15;
    const int hc0  = blockIdx.x * 16;
    const int HW_  = 32768;                // uints per h buffer (B_*H_)

    // Weight fragments: 4 gates x 6 k-iters (4 h + 2 x), loaded once.
    bf16x8 wreg[24];
#pragma unroll
    for (int g = 0; g < 4; ++g)
#pragma unroll
        for (int it = 0; it < 6; ++it) {
            int k = (it < 4) ? (w * 128 + it * 32)
                             : (1024 + w * 64 + (it - 4) * 32);
            wreg[g * 6 + it] = *(const bf16x8*)(
                Wt + (size_t)(g * H_ + hc0 + lcol) * KTOT + k + quad * 8);
        }

    // Epilogue mapping: 512 threads = one (batch,col) element each.
    const int eb = tid >> 4, ec = tid & 15;
    const int col = hc0 + ec;
    float creg = 0.f;
    const float b0 = bias[col];
    const float b1 = bias[H_ + col];
    const float b2 = bias[2 * H_ + col];
    const float b3 = bias[3 * H_ + col];
    const int slm1 = seqlen[eb] - 1;
    // LDS stage index (destination-ordered within this block's h region).
    const int stageIdx = (eb >> 4) * 256 + ((ec >> 3) * 16 + (eb & 15)) * 8 +
                         (ec & 7);
    // Wave0 store-phase constants (ull index within h buffer).
    const int kbB  = (hc0 >> 5) * 1024;    // k-block base (uints)
    const int qlo  = (hc0 >> 4) & 1;       // which quad-pair within k-block
    const int QU   = (kbB >> 1) + qlo * 128;  // ull base of this block's region
    // Flag slots: producer block b -> flags[(b>>3)*16 + (b&7)] (64B/group).
    const int myflag = ((blockIdx.x >> 3) << 4) | (blockIdx.x & 7);
    const unsigned* pollp = flags + w * 16 + (lane & 7);

#pragma unroll 1
    for (int t = 0; t < T_; ++t) {
        const unsigned* hr = hpk + (size_t)(t & 1) * HW_;
        unsigned*       hw = hpk + (size_t)((t + 1) & 1) * HW_;

        f32x4 acc[8];
#pragma unroll
        for (int i = 0; i < 8; ++i) acc[i] = (f32x4){0.f, 0.f, 0.f, 0.f};

        // ---- x part: independent of h(t-1), fills the wait window ----
#pragma unroll
        for (int itx = 0; itx < 2; ++itx) {
            int kx = w * 64 + itx * 32 + quad * 8;
            union { uint4 q[2]; unsigned short s[16]; } u0, u1;
            const unsigned* p0 = Xpk + ((size_t)lcol * T_ + t) * D_ + kx;
            const unsigned* p1 = Xpk + ((size_t)(lcol + 16) * T_ + t) * D_ + kx;
            u0.q[0] = *(const uint4*)p0;
            u0.q[1] = *(const uint4*)(p0 + 4);
            u1.q[0] = *(const uint4*)p1;
            u1.q[1] = *(const uint4*)(p1 + 4);
            bf16x8 a0h, a0l, a1h, a1l;
            unpack16(u0.s, &a0h, &a0l);
            unpack16(u1.s, &a1h, &a1l);
#pragma unroll
            for (int g = 0; g < 4; ++g) {
                bf16x8 wv = wreg[g * 6 + 4 + itx];
                acc[g * 2]     = MFMA16(a0h, wv, acc[g * 2]);
                acc[g * 2]     = MFMA16(a0l, wv, acc[g * 2]);
                acc[g * 2 + 1] = MFMA16(a1h, wv, acc[g * 2 + 1]);
                acc[g * 2 + 1] = MFMA16(a1l, wv, acc[g * 2 + 1]);
            }
        }

        // ---- wait for THIS wave's 8 producers only (tight spin) ----
        {
            const unsigned tgt = (unsigned)t;
            for (;;) {
                unsigned v = __hip_atomic_load(pollp, __ATOMIC_RELAXED,
                                               __HIP_MEMORY_SCOPE_AGENT);
                if (__all((int)(v >= tgt))) break;
            }
            asm volatile("" ::: "memory");
        }

        // ---- h part: issue all 8 fragment loads, then unpack + MFMA ----
        union Raw { unsigned long long u[4]; unsigned short s[16]; };
        Raw r[8];
#pragma unroll
        for (int it = 0; it < 4; ++it) {
            const unsigned long long* q = (const unsigned long long*)(
                hr + (w * 4 + it) * 1024 + lane * 8);
#pragma unroll
            for (int j = 0; j < 4; ++j)
                r[it * 2].u[j] = __hip_atomic_load(
                    q + j, __ATOMIC_RELAXED, __HIP_MEMORY_SCOPE_AGENT);
#pragma unroll
            for (int j = 0; j < 4; ++j)
                r[it * 2 + 1].u[j] = __hip_atomic_load(
                    q + 256 + j, __ATOMIC_RELAXED, __HIP_MEMORY_SCOPE_AGENT);
        }
#pragma unroll
        for (int it = 0; it < 4; ++it) {
            bf16x8 a0h, a0l, a1h, a1l;
            unpack16(r[it * 2].s, &a0h, &a0l);
            unpack16(r[it * 2 + 1].s, &a1h, &a1l);
#pragma unroll
            for (int g = 0; g < 4; ++g) {
                bf16x8 wv = wreg[g * 6 + it];
                acc[g * 2]     = MFMA16(a0h, wv, acc[g * 2]);
                acc[g * 2]     = MFMA16(a0l, wv, acc[g * 2]);
                acc[g * 2 + 1] = MFMA16(a1h, wv, acc[g * 2 + 1]);
                acc[g * 2 + 1] = MFMA16(a1l, wv, acc[g * 2 + 1]);
            }
        }

#pragma unroll
        for (int g = 0; g < 4; ++g)
#pragma unroll
            for (int r4 = 0; r4 < 4; ++r4) {
                zpart[w][g][quad * 4 + r4][lcol]      = acc[g * 2][r4];
                zpart[w][g][16 + quad * 4 + r4][lcol] = acc[g * 2 + 1][r4];
            }
        __syncthreads();  // A: zpart complete

        // Epilogue (all 512 threads).
        float zi = b0, zf = b1, zg = b2, zo = b3;
#pragma unroll
        for (int ss = 0; ss < 8; ++ss) {
            zi += zpart[ss][0][eb][ec];
            zf += zpart[ss][1][eb][ec];
            zg += zpart[ss][2][eb][ec];
            zo += zpart[ss][3][eb][ec];
        }
        float ig = 1.f / (1.f + __expf(-zi));
        float fg = 1.f / (1.f + __expf(-zf));
        float og = 1.f / (1.f + __expf(-zo));
        float gg = 1.f - 2.f / (__expf(2.f * zg) + 1.f);
        creg = fg * creg + ig * gg;
        float hn = og * (1.f - 2.f / (__expf(2.f * creg) + 1.f));
        bf16_t hh = (bf16_t)hn;
        bf16_t hl = (bf16_t)(hn - (float)hh);
        unsigned pk = (unsigned)__builtin_bit_cast(unsigned short, hh) |
                      ((unsigned)__builtin_bit_cast(unsigned short, hl) << 16);
        stage[stageIdx] = pk;
        if (slm1 == t) out[eb * H_ + col] = hn;

        __syncthreads();  // C: stage complete (zpart reads also done)

        // Wave 0 alone: 4 rounds x contiguous 512B of proven 8B agent
        // atomic stores (byte-identical layout to R5's tid<256 store),
        // drain OWN vmcnt, post flag. Waves 1-7 race ahead into t+1's
        // x-phase; next syncA re-couples the block.
        if (w == 0) {
            const unsigned long long* sp = (const unsigned long long*)stage;
            unsigned long long* hwu = (unsigned long long*)hw;
#pragma unroll
            for (int j = 0; j < 4; ++j) {
                unsigned long long val = sp[j * 64 + lane];
                __hip_atomic_store(
                    hwu + QU + (j >> 1) * 256 + (j & 1) * 64 + lane, val,
                    __ATOMIC_RELAXED, __HIP_MEMORY_SCOPE_AGENT);
            }
            asm volatile("s_waitcnt vmcnt(0)" ::: "memory");
            if (lane == 0)
                __hip_atomic_store(flags + myflag, (unsigned)(t + 1),
                                   __ATOMIC_RELAXED, __HIP_MEMORY_SCOPE_AGENT);
        }
    }
}

// ---------------------------------------------------------------------------
extern "C" void kernel_launch(void* const* d_in, const int* in_sizes, int n_in,
                              void* d_out, int out_size, void* d_ws, size_t ws_size,
                              hipStream_t stream) {
    const float* inputs = (const float*)d_in[0];
    const int*   seqlen = (const int*)d_in[1];
    const float* Wx     = (const float*)d_in[2];
    const float* Wh     = (const float*)d_in[3];
    const float* bias   = (const float*)d_in[4];
    float* out = (float*)d_out;

    char* ws = (char*)d_ws;
    size_t o = 0;
    bf16_t*   Wt    = (bf16_t*)(ws + o);   o += (size_t)N4H * KTOT * 2;   // 12.6MB
    unsigned* Xpk   = (unsigned*)(ws + o); o += (size_t)B_ * T_ * D_ * 4; // 33.6MB
    unsigned* hpk   = (unsigned*)(ws + o); o += (size_t)2 * B_ * H_ * 4;  // 256KB
    unsigned* flags = (unsigned*)(ws + o); o += 4096;

    wconv_kernel<<<dim3(48, 128), dim3(32, 8), 0, stream>>>(Wx, Wh, Wt);
    xconv_kernel<<<(B_ * T_ * D_ / 4) / 256, 256, 0, stream>>>(
        (const float4*)inputs, (uint4*)Xpk);
    hipMemsetAsync(hpk, 0, (size_t)B_ * H_ * 4, stream);  // ping p=0 zeros
    hipMemsetAsync(flags, 0, 4096, stream);               // readiness flags

    lstm_kernel<<<NBLK, 512, 0, stream>>>(Wt, Xpk, hpk, bias, seqlen, out, flags);
}